// Round 2
// baseline (1181.278 us; speedup 1.0000x reference)
//
#include <hip/hip_runtime.h>

// SeqAutoEncoder on MI355X.
// Structure: B=64, T=2048, D=256, H=30, G=4H=120, NOUT=5.
//   K1 gemm_pre : pre1 = seq @ enc_W1[0:256] + enc_b1   (parallel, 8 GFLOP fp32)
//   K2 scan     : blocks 0..63 = encoder chains (L1+L2 fused, latent epilogue)
//                 block  64    = decoder chain (zero input -> batch-independent)
//                 2 waves/block, software-pipelined: wave0=L1(t+1) || wave1=L2(t)
//   K3 bcast    : dec_out[b,t] = dec_seq[t]
// ws layout: pre1 [64*2048*120] f32 (62.9 MB), then dec_seq [2048] f32.

#define BB 64
#define TT 2048
#define DD 256
#define HH 30
#define GG 120
#define PRE_ELEMS (64u * 2048u * 120u)

__device__ __forceinline__ float fast_exp(float x) {
  return __builtin_amdgcn_exp2f(x * 1.442695040888963f);
}
__device__ __forceinline__ float fast_rcp(float x) {
  return __builtin_amdgcn_rcpf(x);
}
__device__ __forceinline__ float sigm(float x) {
  return fast_rcp(1.0f + fast_exp(-x));
}
__device__ __forceinline__ float tanh_f(float x) {
  // (e^2x - 1)/(e^2x + 1); exp2 overflow -> inf -> rcp -> 0 -> +/-1, correct limits
  return 1.0f - 2.0f * fast_rcp(1.0f + fast_exp(2.0f * x));
}

// ---------------- K1: pre1 = seq @ Wx1 + b1 ----------------
// Tile: 128 rows x 120 cols, BK=32, 256 threads (240 compute: 30x8, TM=16 TN=4).
__global__ __launch_bounds__(256) void gemm_pre(const float* __restrict__ A,
                                                const float* __restrict__ W,
                                                const float* __restrict__ bias,
                                                float* __restrict__ out) {
  __shared__ __align__(16) float sA[32 * 132];  // [k][row], pad 132 keeps b128 reads aligned
  __shared__ __align__(16) float sW[32 * 120];  // [k][n]
  const int tid = threadIdx.x;
  const int row0 = blockIdx.x * 128;
  const int tx = tid % 30;
  const int ty = tid / 30;
  const bool comp = tid < 240;
  float4 acc[16];
#pragma unroll
  for (int i = 0; i < 16; ++i) acc[i] = make_float4(0.f, 0.f, 0.f, 0.f);
  const float4* A4 = (const float4*)A;
  const float4* W4 = (const float4*)W;
  const int rload = tid >> 3;  // 0..31
  const int kq = tid & 7;      // 0..7 (float4 within 32-wide k chunk)
  for (int k0 = 0; k0 < 256; k0 += 32) {
    __syncthreads();
    // stage W chunk: rows k0..k0+31 x 120 cols, contiguous = 960 float4
#pragma unroll
    for (int it = 0; it < 4; ++it) {
      int idx = tid + it * 256;
      if (idx < 960) ((float4*)sW)[idx] = W4[k0 * 30 + idx];
    }
    // stage A chunk transposed: sA[k][row]
#pragma unroll
    for (int m = 0; m < 4; ++m) {
      int rr = rload + m * 32;
      float4 v = A4[(size_t)(row0 + rr) * 64 + (k0 >> 2) + kq];
      int kk = kq * 4;
      sA[(kk + 0) * 132 + rr] = v.x;
      sA[(kk + 1) * 132 + rr] = v.y;
      sA[(kk + 2) * 132 + rr] = v.z;
      sA[(kk + 3) * 132 + rr] = v.w;
    }
    __syncthreads();
    if (comp) {
#pragma unroll 4
      for (int k = 0; k < 32; ++k) {
        const float4 w = ((const float4*)sW)[k * 30 + tx];
        const float4* a4 = (const float4*)&sA[k * 132 + ty * 16];
        float4 a0 = a4[0], a1 = a4[1], a2 = a4[2], a3 = a4[3];
        float av[16] = {a0.x, a0.y, a0.z, a0.w, a1.x, a1.y, a1.z, a1.w,
                        a2.x, a2.y, a2.z, a2.w, a3.x, a3.y, a3.z, a3.w};
#pragma unroll
        for (int i = 0; i < 16; ++i) {
          acc[i].x = fmaf(av[i], w.x, acc[i].x);
          acc[i].y = fmaf(av[i], w.y, acc[i].y);
          acc[i].z = fmaf(av[i], w.z, acc[i].z);
          acc[i].w = fmaf(av[i], w.w, acc[i].w);
        }
      }
    }
  }
  if (comp) {
    const float4 bv = ((const float4*)bias)[tx];
#pragma unroll
    for (int i = 0; i < 16; ++i) {
      int row = row0 + ty * 16 + i;
      float4 r;
      r.x = acc[i].x + bv.x;
      r.y = acc[i].y + bv.y;
      r.z = acc[i].z + bv.z;
      r.w = acc[i].w + bv.w;
      ((float4*)out)[(size_t)row * 30 + tx] = r;
    }
  }
}

// ---------------- K2: fused recurrent scan ----------------
// 65 blocks x 128 threads (2 waves). Lane l<60 owns gate columns (l, l+60):
//   colA = l    : l<30 -> i gate, 30<=l<60 -> j gate
//   colB = l+60 : l<30 -> f gate, 30<=l<60 -> o gate
// wave0: layer-1 step t+1 (input term prefetched from pre1, depth-2)
// wave1: layer-2 step t   (consumes h1(t) via parity-buffered LDS)
__global__ __launch_bounds__(128, 1) void scan_kernel(
    const float* __restrict__ pre, const float* __restrict__ enc_W1,
    const float* __restrict__ enc_W2, const float* __restrict__ enc_b2,
    const float* __restrict__ enc_Wd, const float* __restrict__ enc_bd,
    const float* __restrict__ dec_W1, const float* __restrict__ dec_b1,
    const float* __restrict__ dec_W2, const float* __restrict__ dec_b2,
    float* __restrict__ out, float* __restrict__ dec_seq) {
  __shared__ __align__(16) float h1buf[2][32];
  __shared__ __align__(16) float h2buf[32];
  const int tid = threadIdx.x;
  const int wave = tid >> 6;
  const int lane = tid & 63;
  const int blk = blockIdx.x;
  const bool isdec = (blk == BB);
  const bool act = lane < 60;
  if (tid < 32) {
    h1buf[0][tid] = 0.f;
    h1buf[1][tid] = 0.f;
    h2buf[tid] = 0.f;
  }
  float wA[60], wB[60];  // wave0 uses [0..29], wave1 [0..59]; register-resident
  float biasA = 0.f, biasB = 0.f;
  float c = 0.f;  // c1 (wave0) / c2 (wave1), lanes < 30
  const float* pr = pre + (size_t)blk * TT * GG;  // valid only for enc blocks
  if (wave == 0) {
    const float* Wsrc = isdec ? (dec_W1 + GG) : (enc_W1 + 256 * GG);
    if (act) {
#pragma unroll
      for (int k = 0; k < 30; ++k) {
        wA[k] = Wsrc[k * GG + lane];
        wB[k] = Wsrc[k * GG + lane + 60];
      }
      if (isdec) {
        biasA = dec_b1[lane];
        biasB = dec_b1[lane + 60];
      }
    }
  } else {
    const float* Wsrc = isdec ? dec_W2 : enc_W2;
    const float* bsrc = isdec ? dec_b2 : enc_b2;
    if (act) {
#pragma unroll
      for (int k = 0; k < 60; ++k) {
        wA[k] = Wsrc[k * GG + lane];
        wB[k] = Wsrc[k * GG + lane + 60];
      }
      biasA = bsrc[lane];
      biasB = bsrc[lane + 60];
    }
  }
  // depth-2 prefetch of pre1 (encoder wave0 only); named scalars -> registers
  float pA0 = biasA, pB0 = biasB, pA1 = biasA, pB1 = biasB;
  if (wave == 0 && !isdec && act) {
    pA0 = pr[lane];
    pB0 = pr[lane + 60];
    pA1 = pr[GG + lane];
    pB1 = pr[GG + lane + 60];
  }

  auto l1step = [&](int s, float& pa, float& pb) {
    const int rp = (s + 1) & 1, wp = s & 1;
    const float4* hp = (const float4*)&h1buf[rp][0];
    float4 q0 = hp[0], q1 = hp[1], q2 = hp[2], q3 = hp[3], q4 = hp[4], q5 = hp[5],
           q6 = hp[6], q7 = hp[7];
    float hv[32] = {q0.x, q0.y, q0.z, q0.w, q1.x, q1.y, q1.z, q1.w,
                    q2.x, q2.y, q2.z, q2.w, q3.x, q3.y, q3.z, q3.w,
                    q4.x, q4.y, q4.z, q4.w, q5.x, q5.y, q5.z, q5.w,
                    q6.x, q6.y, q6.z, q6.w, q7.x, q7.y, q7.z, q7.w};
    float aA = pa, aB = pb;
    // refill prefetch slot for step s+2 (issues early, consumed 2 supersteps later)
    if (!isdec && act) {
      int s2 = s + 2;
      if (s2 < TT) {
        pa = pr[s2 * GG + lane];
        pb = pr[s2 * GG + lane + 60];
      }
    }
#pragma unroll
    for (int k = 0; k < 30; ++k) {
      aA = fmaf(hv[k], wA[k], aA);
      aB = fmaf(hv[k], wB[k], aB);
    }
    float p1, p2;
    if (lane < 30) {
      p1 = sigm(aA);          // i
      p2 = sigm(aB + 1.0f);   // f (+forget_bias)
    } else {
      p1 = tanh_f(aA);        // j
      p2 = sigm(aB);          // o
    }
    float jv = __shfl(p1, lane + 30, 64);
    float ov = __shfl(p2, lane + 30, 64);
    if (lane < 30) {
      c = c * p2 + p1 * jv;
      float hnew = tanh_f(c) * ov;
      h1buf[wp][lane] = hnew;
    }
  };

  auto l2step = [&](int t) {
    const int rp = t & 1;  // parity written by L1 at step t
    const float4* hp1 = (const float4*)&h1buf[rp][0];
    const float4* hp2 = (const float4*)&h2buf[0];
    float4 q0 = hp1[0], q1 = hp1[1], q2 = hp1[2], q3 = hp1[3], q4 = hp1[4],
           q5 = hp1[5], q6 = hp1[6], q7 = hp1[7];
    float4 r0 = hp2[0], r1 = hp2[1], r2 = hp2[2], r3 = hp2[3], r4 = hp2[4],
           r5 = hp2[5], r6 = hp2[6], r7 = hp2[7];
    float h1v[32] = {q0.x, q0.y, q0.z, q0.w, q1.x, q1.y, q1.z, q1.w,
                     q2.x, q2.y, q2.z, q2.w, q3.x, q3.y, q3.z, q3.w,
                     q4.x, q4.y, q4.z, q4.w, q5.x, q5.y, q5.z, q5.w,
                     q6.x, q6.y, q6.z, q6.w, q7.x, q7.y, q7.z, q7.w};
    float h2v[32] = {r0.x, r0.y, r0.z, r0.w, r1.x, r1.y, r1.z, r1.w,
                     r2.x, r2.y, r2.z, r2.w, r3.x, r3.y, r3.z, r3.w,
                     r4.x, r4.y, r4.z, r4.w, r5.x, r5.y, r5.z, r5.w,
                     r6.x, r6.y, r6.z, r6.w, r7.x, r7.y, r7.z, r7.w};
    float aA = biasA, aB = biasB;
#pragma unroll
    for (int k = 0; k < 30; ++k) {
      aA = fmaf(h1v[k], wA[k], aA);
      aB = fmaf(h1v[k], wB[k], aB);
    }
#pragma unroll
    for (int k = 0; k < 30; ++k) {
      aA = fmaf(h2v[k], wA[30 + k], aA);
      aB = fmaf(h2v[k], wB[30 + k], aB);
    }
    float p1, p2;
    if (lane < 30) {
      p1 = sigm(aA);
      p2 = sigm(aB + 1.0f);
    } else {
      p1 = tanh_f(aA);
      p2 = sigm(aB);
    }
    float jv = __shfl(p1, lane + 30, 64);
    float ov = __shfl(p2, lane + 30, 64);
    if (lane < 30) {
      c = c * p2 + p1 * jv;
      float hnew = tanh_f(c) * ov;
      h2buf[lane] = hnew;
      if (isdec && lane == HH - 1) dec_seq[t] = hnew;
    }
  };

  // supersteps s=0..TT: wave0 runs L1(s) for s<TT; wave1 runs L2(s-1) for s>=1.
  // One barrier per superstep; h1buf parity prevents read/write overlap.
  for (int ss = 0; ss < TT; ss += 2) {
    __syncthreads();
    if (wave == 0) {
      l1step(ss, pA0, pB0);
    } else if (ss > 0) {
      l2step(ss - 1);
    }
    __syncthreads();
    if (wave == 0) {
      l1step(ss + 1, pA1, pB1);
    } else {
      l2step(ss);
    }
  }
  __syncthreads();
  if (wave == 1) {
    l2step(TT - 1);
    if (!isdec && lane < 5) {  // latent = tanh(h2_last @ enc_Wd + enc_bd)
      float a = enc_bd[lane];
#pragma unroll
      for (int k = 0; k < 30; ++k) a = fmaf(h2buf[k], enc_Wd[k * 5 + lane], a);
      out[BB * TT + blk * 5 + lane] = tanh_f(a);
    }
  }
}

// ---------------- K3: broadcast decoder chain to all batch rows ----------------
// float4 stores: 32768 stores instead of 131072. i4 = b*512 + t4; t4 = i4 & 511.
__global__ __launch_bounds__(256) void bcast_kernel(const float* __restrict__ dec_seq,
                                                    float* __restrict__ out) {
  int i4 = blockIdx.x * 256 + threadIdx.x;  // 32768 float4s
  ((float4*)out)[i4] = ((const float4*)dec_seq)[i4 & (TT / 4 - 1)];
}

extern "C" void kernel_launch(void* const* d_in, const int* in_sizes, int n_in,
                              void* d_out, int out_size, void* d_ws, size_t ws_size,
                              hipStream_t stream) {
  const float* seq = (const float*)d_in[0];
  const float* enc_W1 = (const float*)d_in[1];
  const float* enc_b1 = (const float*)d_in[2];
  const float* enc_W2 = (const float*)d_in[3];
  const float* enc_b2 = (const float*)d_in[4];
  const float* enc_Wd = (const float*)d_in[5];
  const float* enc_bd = (const float*)d_in[6];
  // d_in[7] dec_Wd, d_in[8] dec_bd: dead code in reference (vec2 unused)
  const float* dec_W1 = (const float*)d_in[9];
  const float* dec_b1 = (const float*)d_in[10];
  const float* dec_W2 = (const float*)d_in[11];
  const float* dec_b2 = (const float*)d_in[12];
  float* out = (float*)d_out;
  float* pre = (float*)d_ws;               // 62.9 MB
  float* dec_seq = pre + PRE_ELEMS;        // 8 KB

  gemm_pre<<<dim3(1024), dim3(256), 0, stream>>>(seq, enc_W1, enc_b1, pre);
  scan_kernel<<<dim3(65), dim3(128), 0, stream>>>(pre, enc_W1, enc_W2, enc_b2,
                                                  enc_Wd, enc_bd, dec_W1, dec_b1,
                                                  dec_W2, dec_b2, out, dec_seq);
  bcast_kernel<<<dim3(128), dim3(256), 0, stream>>>(dec_seq, out);
}